// Round 2
// baseline (322.837 us; speedup 1.0000x reference)
//
#include <hip/hip_runtime.h>
#include <math.h>

#define BATCH 256
#define VOCAB 128000
#define V4 (VOCAB / 4)
#define NTHREADS 1024
#define NWAVES (NTHREADS / 64)

typedef float vfloat4 __attribute__((ext_vector_type(4)));

__global__ __launch_bounds__(NTHREADS) void sampler_kernel(
    const float* __restrict__ logits,
    const float* __restrict__ temps,
    const float* __restrict__ noise,
    float* __restrict__ out_tokens,
    float* __restrict__ out_probs)
{
    const int b   = blockIdx.x;
    const int tid = threadIdx.x;
    const int wave = tid >> 6;
    const int lane = tid & 63;

    const float t      = temps[b];
    const float safe_t = (t == 0.0f) ? 1.0f : t;
    const float inv_t  = 1.0f / safe_t;

    const vfloat4* lg4 = (const vfloat4*)(logits + (size_t)b * VOCAB);
    const vfloat4* nz4 = (const vfloat4*)(noise  + (size_t)b * VOCAB);
    vfloat4*       pb4 = (vfloat4*)(out_probs + (size_t)b * VOCAB);

    // ---------------- Phase 1: logits only — online softmax (m,s) + greedy argmax
    float m = -INFINITY, s = 0.0f;
    float gv = -INFINITY; int gi = 0;

    for (int i = tid; i < V4; i += NTHREADS) {
        vfloat4 x4 = lg4[i];
#pragma unroll
        for (int j = 0; j < 4; ++j) {
            const int   idx = 4 * i + j;
            const float x   = x4[j];
            const float sc  = x * inv_t;
            if (x > gv) { gv = x; gi = idx; }          // thread-local idx increases: '>' keeps first
            const float mn = fmaxf(m, sc);             // branchless online softmax
            s = s * expf(m - mn) + expf(sc - mn);
            m = mn;
        }
    }

    // wave-level reduction (64 lanes)
#pragma unroll
    for (int off = 32; off >= 1; off >>= 1) {
        float m2  = __shfl_down(m,  off);
        float s2  = __shfl_down(s,  off);
        float gv2 = __shfl_down(gv, off);
        int   gi2 = __shfl_down(gi, off);
        float mn = fmaxf(m, m2);
        s = s * expf(m - mn) + s2 * expf(m2 - mn);
        m = mn;
        if (gv2 > gv || (gv2 == gv && gi2 < gi)) { gv = gv2; gi = gi2; }
    }

    __shared__ float sm[NWAVES], ss[NWAVES], sgv[NWAVES];
    __shared__ int   sgi[NWAVES];
    __shared__ float bM, binvS;
    __shared__ int   bGI;
    if (lane == 0) { sm[wave] = m; ss[wave] = s; sgv[wave] = gv; sgi[wave] = gi; }
    __syncthreads();
    if (tid == 0) {
        float M = sm[0], S = ss[0], GV = sgv[0]; int GI = sgi[0];
        for (int w = 1; w < NWAVES; ++w) {
            float mn = fmaxf(M, sm[w]);
            S = S * expf(M - mn) + ss[w] * expf(sm[w] - mn);
            M = mn;
            if (sgv[w] > GV || (sgv[w] == GV && sgi[w] < GI)) { GV = sgv[w]; GI = sgi[w]; }
        }
        bM = M; binvS = 1.0f / S; bGI = GI;
    }
    __syncthreads();
    const float M    = bM;
    const float invS = binvS;

    // ---------------- Phase 2: re-read logits (L3-warm) + stream noise:
    // write probs, Gumbel-max argmax
    float sv = -INFINITY; int si = 0;

    for (int i = tid; i < V4; i += NTHREADS) {
        vfloat4 x4 = lg4[i];
        vfloat4 u4 = __builtin_nontemporal_load(&nz4[i]);
        vfloat4 p;
#pragma unroll
        for (int j = 0; j < 4; ++j) {
            const int   idx = 4 * i + j;
            const float sc  = x4[j] * inv_t;
            p[j] = expf(sc - M) * invS;
            const float g = -logf(-logf(u4[j]));
            const float z = sc + g;
            if (z > sv) { sv = z; si = idx; }
        }
        __builtin_nontemporal_store(p, &pb4[i]);
    }

    // reduce sample argmax
#pragma unroll
    for (int off = 32; off >= 1; off >>= 1) {
        float sv2 = __shfl_down(sv, off);
        int   si2 = __shfl_down(si, off);
        if (sv2 > sv || (sv2 == sv && si2 < si)) { sv = sv2; si = si2; }
    }
    __shared__ float ssv[NWAVES];
    __shared__ int   ssi[NWAVES];
    if (lane == 0) { ssv[wave] = sv; ssi[wave] = si; }
    __syncthreads();
    if (tid == 0) {
        float SV = ssv[0]; int SI = ssi[0];
        for (int w = 1; w < NWAVES; ++w) {
            if (ssv[w] > SV || (ssv[w] == SV && ssi[w] < SI)) { SV = ssv[w]; SI = ssi[w]; }
        }
        const int token = (t == 0.0f) ? bGI : SI;
        out_tokens[b] = (float)token;
    }
}

extern "C" void kernel_launch(void* const* d_in, const int* in_sizes, int n_in,
                              void* d_out, int out_size, void* d_ws, size_t ws_size,
                              hipStream_t stream) {
    const float* logits = (const float*)d_in[0];
    const float* temps  = (const float*)d_in[1];
    const float* noise  = (const float*)d_in[2];
    float* out = (float*)d_out;
    // d_out layout: [tokens (BATCH floats)] [probs (BATCH*VOCAB floats)]
    sampler_kernel<<<BATCH, NTHREADS, 0, stream>>>(logits, temps, noise,
                                                   out, out + BATCH);
}

// Round 3
// 318.505 us; speedup vs baseline: 1.0136x; 1.0136x over previous
//
#include <hip/hip_runtime.h>
#include <math.h>

#define BATCH 256
#define VOCAB 128000
#define V4 (VOCAB / 4)
#define NTHREADS 1024
#define NWAVES (NTHREADS / 64)

typedef float vfloat4 __attribute__((ext_vector_type(4)));

__global__ __launch_bounds__(NTHREADS) void sampler_kernel(
    const float* __restrict__ logits,
    const float* __restrict__ temps,
    const float* __restrict__ noise,
    float* __restrict__ out_tokens,
    float* __restrict__ out_probs)
{
    const int b   = blockIdx.x;
    const int tid = threadIdx.x;
    const int wave = tid >> 6;
    const int lane = tid & 63;

    const float t      = temps[b];
    const float safe_t = (t == 0.0f) ? 1.0f : t;
    const float inv_t  = 1.0f / safe_t;

    const vfloat4* lg4 = (const vfloat4*)(logits + (size_t)b * VOCAB);
    const vfloat4* nz4 = (const vfloat4*)(noise  + (size_t)b * VOCAB);
    vfloat4*       pb4 = (vfloat4*)(out_probs + (size_t)b * VOCAB);

    // ---------------- Phase 1: logits only — online softmax (m,s) + greedy argmax
    // fast-intrinsic exp (v_exp_f32): ~2 VALU ops vs ~18 for libm expf
    float m = -INFINITY, s = 0.0f;
    float gv = -INFINITY; int gi = 0;

    for (int i = tid; i < V4; i += NTHREADS) {
        vfloat4 x4 = lg4[i];
#pragma unroll
        for (int j = 0; j < 4; ++j) {
            const int   idx = 4 * i + j;
            const float x   = x4[j];
            const float sc  = x * inv_t;
            if (x > gv) { gv = x; gi = idx; }          // thread-local idx increases: '>' keeps first
            const float mn = fmaxf(m, sc);             // branchless online softmax
            s = s * __expf(m - mn) + __expf(sc - mn);
            m = mn;
        }
    }

    // wave-level reduction (64 lanes)
#pragma unroll
    for (int off = 32; off >= 1; off >>= 1) {
        float m2  = __shfl_down(m,  off);
        float s2  = __shfl_down(s,  off);
        float gv2 = __shfl_down(gv, off);
        int   gi2 = __shfl_down(gi, off);
        float mn = fmaxf(m, m2);
        s = s * __expf(m - mn) + s2 * __expf(m2 - mn);
        m = mn;
        if (gv2 > gv || (gv2 == gv && gi2 < gi)) { gv = gv2; gi = gi2; }
    }

    __shared__ float sm[NWAVES], ss[NWAVES], sgv[NWAVES];
    __shared__ int   sgi[NWAVES];
    __shared__ float bM, binvS;
    __shared__ int   bGI;
    if (lane == 0) { sm[wave] = m; ss[wave] = s; sgv[wave] = gv; sgi[wave] = gi; }
    __syncthreads();
    if (tid == 0) {
        float M = sm[0], S = ss[0], GV = sgv[0]; int GI = sgi[0];
        for (int w = 1; w < NWAVES; ++w) {
            float mn = fmaxf(M, sm[w]);
            S = S * __expf(M - mn) + ss[w] * __expf(sm[w] - mn);
            M = mn;
            if (sgv[w] > GV || (sgv[w] == GV && sgi[w] < GI)) { GV = sgv[w]; GI = sgi[w]; }
        }
        bM = M; binvS = 1.0f / S; bGI = GI;
    }
    __syncthreads();
    const float M    = bM;
    const float invS = binvS;

    // ---------------- Phase 2: re-read logits (L3-warm) + stream noise:
    // write probs, Gumbel-max argmax
    float sv = -INFINITY; int si = 0;

    for (int i = tid; i < V4; i += NTHREADS) {
        vfloat4 x4 = lg4[i];
        vfloat4 u4 = __builtin_nontemporal_load(&nz4[i]);
        vfloat4 p;
#pragma unroll
        for (int j = 0; j < 4; ++j) {
            const int   idx = 4 * i + j;
            const float sc  = x4[j] * inv_t;
            p[j] = __expf(sc - M) * invS;
            const float g = -__logf(-__logf(u4[j]));
            const float z = sc + g;
            if (z > sv) { sv = z; si = idx; }
        }
        __builtin_nontemporal_store(p, &pb4[i]);
    }

    // reduce sample argmax
#pragma unroll
    for (int off = 32; off >= 1; off >>= 1) {
        float sv2 = __shfl_down(sv, off);
        int   si2 = __shfl_down(si, off);
        if (sv2 > sv || (sv2 == sv && si2 < si)) { sv = sv2; si = si2; }
    }
    __shared__ float ssv[NWAVES];
    __shared__ int   ssi[NWAVES];
    if (lane == 0) { ssv[wave] = sv; ssi[wave] = si; }
    __syncthreads();
    if (tid == 0) {
        float SV = ssv[0]; int SI = ssi[0];
        for (int w = 1; w < NWAVES; ++w) {
            if (ssv[w] > SV || (ssv[w] == SV && ssi[w] < SI)) { SV = ssv[w]; SI = ssi[w]; }
        }
        const int token = (t == 0.0f) ? bGI : SI;
        out_tokens[b] = (float)token;
    }
}

extern "C" void kernel_launch(void* const* d_in, const int* in_sizes, int n_in,
                              void* d_out, int out_size, void* d_ws, size_t ws_size,
                              hipStream_t stream) {
    const float* logits = (const float*)d_in[0];
    const float* temps  = (const float*)d_in[1];
    const float* noise  = (const float*)d_in[2];
    float* out = (float*)d_out;
    // d_out layout: [tokens (BATCH floats)] [probs (BATCH*VOCAB floats)]
    sampler_kernel<<<BATCH, NTHREADS, 0, stream>>>(logits, temps, noise,
                                                   out, out + BATCH);
}